// Round 3
// baseline (4196.253 us; speedup 1.0000x reference)
//
#include <hip/hip_runtime.h>
#include <math.h>

constexpr int Bc = 4, Nc = 32768, Cc = 256, Hc = 8, CHc = 64, Mc = 64, INNERc = 512;

__device__ __forceinline__ void fma4x4(float acc[4][4], const float4 a, const float4 b) {
  acc[0][0] += a.x*b.x; acc[0][1] += a.x*b.y; acc[0][2] += a.x*b.z; acc[0][3] += a.x*b.w;
  acc[1][0] += a.y*b.x; acc[1][1] += a.y*b.y; acc[1][2] += a.y*b.z; acc[1][3] += a.y*b.w;
  acc[2][0] += a.z*b.x; acc[2][1] += a.z*b.y; acc[2][2] += a.z*b.z; acc[2][3] += a.z*b.w;
  acc[3][0] += a.w*b.x; acc[3][1] += a.w*b.y; acc[3][2] += a.w*b.z; acc[3][3] += a.w*b.w;
}

// ============================================================================
// project_token: per (chunk, h, b): for each 64-token tile:
//   FX = X@Wfx_h + bfx, XM = X@Wx_h + bx  (shared X staging, K=256)
//   logits = XM@Wslice + bsl, /clip(temp); softmax over g (shfl, 16-lane groups)
//   TUacc[g][c] += sum_t sw[t][g]*FX[t][c];  Ssum[g] += sum_t sw[t][g]
// LDS overlay plan (192 rows x 68):
//   rows 0..31 As(X^T) | 32..63 BsF | 64..95 BsX   (stage 1)
//   rows 0..63 FXs[token][c] | 64..127 XMs[c][token] -> Lg[token][g]
//   rows 128..191 Ws2 (Wslice, persistent; reused as Ssum tmp at end)
// ============================================================================
__global__ __launch_bounds__(256)
void project_token_kernel(const float* __restrict__ X, const float* __restrict__ Wfx,
                          const float* __restrict__ bfx, const float* __restrict__ Wx,
                          const float* __restrict__ bx, const float* __restrict__ Wsl,
                          const float* __restrict__ bsl, const float* __restrict__ temp,
                          float* __restrict__ TU, float* __restrict__ Ssum)
{
  __shared__ __align__(16) float smem[192 * 68];  // 52,224 B
  float (*As)[68]  = (float(*)[68])smem;
  float (*BsF)[68] = (float(*)[68])(smem + 32*68);
  float (*BsX)[68] = (float(*)[68])(smem + 64*68);
  float (*FXs)[68] = (float(*)[68])smem;
  float (*XMs)[68] = (float(*)[68])(smem + 64*68);  // [c][token]
  float (*Lg)[68]  = (float(*)[68])(smem + 64*68);  // [token][g]
  float (*Ws2)[68] = (float(*)[68])(smem + 128*68);

  const int t = threadIdx.x, tx = t & 15, ty = t >> 4;
  const int chunk = blockIdx.x, h = blockIdx.y, b = blockIdx.z;
  const int bh = b * Hc + h, colBase = h * 64;
  const int lr = t >> 3, lk = (t & 7) << 2;      // X-tile loader
  const int wk = t >> 4, wc = (t & 15) << 2;     // W-tile loader

  // Wslice persistent in LDS
#pragma unroll
  for (int rep = 0; rep < 4; ++rep) {
    const int v = t + rep * 256, r = v >> 4, c4 = (v & 15) << 2;
    *(float4*)&Ws2[r][c4] = *(const float4*)&Wsl[r * 64 + c4];
  }
  const float invt = 1.0f / fminf(fmaxf(temp[h], 0.1f), 5.0f);
  const float4 bfv = *(const float4*)&bfx[colBase + (tx << 2)];
  const float4 bxv = *(const float4*)&bx[colBase + (tx << 2)];
  const float4 bsv = *(const float4*)&bsl[(tx << 2)];
  const float bf_[4] = {bfv.x, bfv.y, bfv.z, bfv.w};
  const float bx_[4] = {bxv.x, bxv.y, bxv.z, bxv.w};
  const float bs_[4] = {bsv.x, bsv.y, bsv.z, bsv.w};

  float tuacc[4][4] = {};
  float sreg[4] = {};

  for (int tile = 0; tile < 32; ++tile) {
    const int n0 = chunk * 2048 + tile * 64;
    const long xBase = ((long)b * Nc + n0) * Cc;

    // ---- stage 1: FX & XM tiles (shared X staging) ----
    float aF[4][4] = {}, aX[4][4] = {};
    for (int kt = 0; kt < Cc; kt += 32) {
      const float4 x0 = *(const float4*)&X[xBase + (long)lr        * Cc + kt + lk];
      const float4 x1 = *(const float4*)&X[xBase + (long)(lr + 32) * Cc + kt + lk];
      const float4 f0 = *(const float4*)&Wfx[(long)(kt + wk)      * INNERc + colBase + wc];
      const float4 f1 = *(const float4*)&Wfx[(long)(kt + wk + 16) * INNERc + colBase + wc];
      const float4 g0 = *(const float4*)&Wx[(long)(kt + wk)      * INNERc + colBase + wc];
      const float4 g1 = *(const float4*)&Wx[(long)(kt + wk + 16) * INNERc + colBase + wc];
      __syncthreads();   // also guards prev tile's FXs/Lg reads vs As/Bs overwrite
      As[lk+0][lr] = x0.x; As[lk+1][lr] = x0.y; As[lk+2][lr] = x0.z; As[lk+3][lr] = x0.w;
      As[lk+0][lr+32] = x1.x; As[lk+1][lr+32] = x1.y; As[lk+2][lr+32] = x1.z; As[lk+3][lr+32] = x1.w;
      *(float4*)&BsF[wk][wc] = f0; *(float4*)&BsF[wk+16][wc] = f1;
      *(float4*)&BsX[wk][wc] = g0; *(float4*)&BsX[wk+16][wc] = g1;
      __syncthreads();
#pragma unroll
      for (int k = 0; k < 32; ++k) {
        const float4 a = *(const float4*)&As[k][ty << 2];
        fma4x4(aF, a, *(const float4*)&BsF[k][tx << 2]);
        fma4x4(aX, a, *(const float4*)&BsX[k][tx << 2]);
      }
    }
    __syncthreads();  // As/BsF/BsX reads done before FXs/XMs overlay writes
#pragma unroll
    for (int i = 0; i < 4; ++i)
#pragma unroll
      for (int j = 0; j < 4; ++j) {
        FXs[(ty<<2)+i][(tx<<2)+j] = aF[i][j] + bf_[j];   // [token][c]
        XMs[(tx<<2)+j][(ty<<2)+i] = aX[i][j] + bx_[j];   // [c][token]  (transposed!)
      }
    __syncthreads();

    // ---- stage 2: logits[token][g] = XM @ Wslice (contract over c=k) ----
    float l2[4][4] = {};
#pragma unroll
    for (int k = 0; k < 64; ++k) {
      const float4 a = *(const float4*)&XMs[k][ty << 2];   // token quad at channel k
      fma4x4(l2, a, *(const float4*)&Ws2[k][tx << 2]);     // Wsl[c=k][g quad]
    }
    // ---- stage 3: softmax over g (row = 16-lane shfl group, 4 rows/thread) ----
    float e[4][4];
#pragma unroll
    for (int i = 0; i < 4; ++i) {
      float mx = -1e30f;
#pragma unroll
      for (int j = 0; j < 4; ++j) { l2[i][j] = (l2[i][j] + bs_[j]) * invt; mx = fmaxf(mx, l2[i][j]); }
      for (int d = 1; d < 16; d <<= 1) mx = fmaxf(mx, __shfl_xor(mx, d));
      float s = 0.f;
#pragma unroll
      for (int j = 0; j < 4; ++j) { e[i][j] = __expf(l2[i][j] - mx); s += e[i][j]; }
      for (int d = 1; d < 16; d <<= 1) s += __shfl_xor(s, d);
      const float inv = 1.0f / s;
#pragma unroll
      for (int j = 0; j < 4; ++j) { e[i][j] *= inv; sreg[j] += e[i][j]; }
    }
    __syncthreads();  // XMs reads done before Lg overlay write
#pragma unroll
    for (int i = 0; i < 4; ++i)
#pragma unroll
      for (int j = 0; j < 4; ++j) Lg[(ty<<2)+i][(tx<<2)+j] = e[i][j];
    __syncthreads();

    // ---- stage 4: TU contraction (contract over token=k) ----
#pragma unroll
    for (int k = 0; k < 64; ++k) {
      const float4 a = *(const float4*)&Lg[k][ty << 2];     // g quad
      fma4x4(tuacc, a, *(const float4*)&FXs[k][tx << 2]);   // c quad
    }
  }

#pragma unroll
  for (int i = 0; i < 4; ++i)
#pragma unroll
    for (int j = 0; j < 4; ++j)
      atomicAdd(&TU[((long)bh * 64 + (ty<<2)+i) * 64 + (tx<<2)+j], tuacc[i][j]);

  // Ssum reduce over ty (reuse Ws2 rows as tmp)
  __syncthreads();
#pragma unroll
  for (int j = 0; j < 4; ++j) Ws2[ty][(tx<<2)+j] = sreg[j];
  __syncthreads();
  if (t < 64) {
    float s = 0.f;
    for (int r = 0; r < 16; ++r) s += Ws2[r][t];
    atomicAdd(&Ssum[bh * 64 + t], s);
  }
}

// ============================================================================
// att: 32 blocks x 1 wave. token = TU/(S+eps); q/k/v; softmax attention;
// writes OT[bh][c][g] = out_tok[g][c] / (Sx[g]+eps)   (invx folded for out einsum)
// ============================================================================
__global__ __launch_bounds__(64)
void att_kernel(const float* __restrict__ TUx, const float* __restrict__ TUc,
                const float* __restrict__ Sx, const float* __restrict__ Sc,
                const float* __restrict__ Wq, const float* __restrict__ Wk,
                const float* __restrict__ Wv, float* __restrict__ OT)
{
  __shared__ __align__(16) float W[64][68];
  __shared__ __align__(16) float Km[64][68];
  __shared__ __align__(16) float Vm[64][68];
  const int bh = blockIdx.x;
  const int g  = threadIdx.x;
  const float invc = 1.0f / (Sc[bh * 64 + g] + 1e-5f);
  const float invx = 1.0f / (Sx[bh * 64 + g] + 1e-5f);

  // K = token_c @ Wk
  for (int i = 0; i < 64; ++i) W[i][g] = Wk[i * 64 + g];
  __syncthreads();
  {
    float4 a[16]; for (int j = 0; j < 16; ++j) a[j] = make_float4(0,0,0,0);
    for (int c = 0; c < 64; ++c) {
      const float tc = TUc[((long)bh * 64 + g) * 64 + c] * invc;
#pragma unroll
      for (int j = 0; j < 16; ++j) {
        const float4 w4 = *(const float4*)&W[c][j << 2];
        a[j].x += tc*w4.x; a[j].y += tc*w4.y; a[j].z += tc*w4.z; a[j].w += tc*w4.w;
      }
    }
    for (int j = 0; j < 16; ++j) *(float4*)&Km[g][j << 2] = a[j];
  }
  __syncthreads();
  // V = token_c @ Wv
  for (int i = 0; i < 64; ++i) W[i][g] = Wv[i * 64 + g];
  __syncthreads();
  {
    float4 a[16]; for (int j = 0; j < 16; ++j) a[j] = make_float4(0,0,0,0);
    for (int c = 0; c < 64; ++c) {
      const float tc = TUc[((long)bh * 64 + g) * 64 + c] * invc;
#pragma unroll
      for (int j = 0; j < 16; ++j) {
        const float4 w4 = *(const float4*)&W[c][j << 2];
        a[j].x += tc*w4.x; a[j].y += tc*w4.y; a[j].z += tc*w4.z; a[j].w += tc*w4.w;
      }
    }
    for (int j = 0; j < 16; ++j) *(float4*)&Vm[g][j << 2] = a[j];
  }
  __syncthreads();
  // Q = token_x @ Wq (kept in regs)
  for (int i = 0; i < 64; ++i) W[i][g] = Wq[i * 64 + g];
  __syncthreads();
  float4 qa[16]; for (int j = 0; j < 16; ++j) qa[j] = make_float4(0,0,0,0);
  for (int c = 0; c < 64; ++c) {
    const float tq = TUx[((long)bh * 64 + g) * 64 + c] * invx;
#pragma unroll
    for (int j = 0; j < 16; ++j) {
      const float4 w4 = *(const float4*)&W[c][j << 2];
      qa[j].x += tq*w4.x; qa[j].y += tq*w4.y; qa[j].z += tq*w4.z; qa[j].w += tq*w4.w;
    }
  }
  __syncthreads();  // all W reads done; overlay Am on W
  float (*Am)[68] = W;
  float mx = -1e30f;
  for (int m = 0; m < 64; ++m) {
    float s = 0.f;
#pragma unroll
    for (int j = 0; j < 16; ++j) {
      const float4 k4 = *(const float4*)&Km[m][j << 2];
      s += qa[j].x*k4.x + qa[j].y*k4.y + qa[j].z*k4.z + qa[j].w*k4.w;
    }
    s *= 0.125f;               // CH^-0.5
    Am[m][g] = s;              // per-thread column, no cross-thread use
    mx = fmaxf(mx, s);
  }
  float sum = 0.f;
  for (int m = 0; m < 64; ++m) { const float ev = __expf(Am[m][g] - mx); Am[m][g] = ev; sum += ev; }
  float4 oa[16]; for (int j = 0; j < 16; ++j) oa[j] = make_float4(0,0,0,0);
  for (int m = 0; m < 64; ++m) {
    const float am = Am[m][g];
#pragma unroll
    for (int j = 0; j < 16; ++j) {
      const float4 v4 = *(const float4*)&Vm[m][j << 2];
      oa[j].x += am*v4.x; oa[j].y += am*v4.y; oa[j].z += am*v4.z; oa[j].w += am*v4.w;
    }
  }
  const float so = invx / sum;
#pragma unroll
  for (int j = 0; j < 16; ++j) {
    OT[((long)bh * 64 + ((j<<2)+0)) * 64 + g] = oa[j].x * so;
    OT[((long)bh * 64 + ((j<<2)+1)) * 64 + g] = oa[j].y * so;
    OT[((long)bh * 64 + ((j<<2)+2)) * 64 + g] = oa[j].z * so;
    OT[((long)bh * 64 + ((j<<2)+3)) * 64 + g] = oa[j].w * so;
  }
}

// ============================================================================
// wofold: WoT[bh][g][co] = sum_c OT[bh][c][g] * Wo[h*64+c][co]
// ============================================================================
__global__ __launch_bounds__(256)
void wofold_kernel(const float* __restrict__ OT, const float* __restrict__ Wo,
                   float* __restrict__ WoT)
{
  __shared__ __align__(16) float OTs[64][68];
  __shared__ __align__(16) float Wos[64][68];
  const int t = threadIdx.x, tx = t & 15, ty = t >> 4;
  const int cot = blockIdx.x * 64, bh = blockIdx.y, h = bh & 7;
#pragma unroll
  for (int rep = 0; rep < 4; ++rep) {
    const int v = t + rep * 256, r = v >> 4, q4 = (v & 15) << 2;
    *(float4*)&OTs[r][q4] = *(const float4*)&OT[((long)bh * 64 + r) * 64 + q4];
    *(float4*)&Wos[r][q4] = *(const float4*)&Wo[(long)(h * 64 + r) * 256 + cot + q4];
  }
  __syncthreads();
  float acc[4][4] = {};
#pragma unroll
  for (int k = 0; k < 64; ++k) {
    const float4 a = *(const float4*)&OTs[k][ty << 2];   // g quad
    fma4x4(acc, a, *(const float4*)&Wos[k][tx << 2]);    // co quad
  }
#pragma unroll
  for (int i = 0; i < 4; ++i) {
    const float4 o = make_float4(acc[i][0], acc[i][1], acc[i][2], acc[i][3]);
    *(float4*)&WoT[((long)bh * 64 + (ty<<2)+i) * 256 + cot + (tx<<2)] = o;
  }
}

// ============================================================================
// outx: per (ntile, b): recompute sw_x per head, contract with WoT:
//   out[n][co] = bo[co] + sum_h sum_g sw_raw[n][g] * WoT[bh][g][co]
// ============================================================================
__global__ __launch_bounds__(256)
void outx_kernel(const float* __restrict__ X, const float* __restrict__ Wx,
                 const float* __restrict__ bx, const float* __restrict__ Wsl,
                 const float* __restrict__ bsl, const float* __restrict__ temp,
                 const float* __restrict__ WoT, const float* __restrict__ bo,
                 float* __restrict__ out)
{
  __shared__ __align__(16) float smem[192 * 68];
  float (*As)[68]  = (float(*)[68])smem;
  float (*Bs)[68]  = (float(*)[68])(smem + 32*68);
  float (*XMs)[68] = (float(*)[68])(smem + 64*68);  // [c][token]
  float (*LgT)[68] = (float(*)[68])(smem + 64*68);  // [g][token]
  float (*Ws2)[68] = (float(*)[68])(smem + 128*68);
  float (*WTs)[264] = (float(*)[264])smem;           // 16x264 <= 64x68 region

  const int t = threadIdx.x, tx = t & 15, ty = t >> 4;
  const int n0 = blockIdx.x * 64, b = blockIdx.y;
  const int lr = t >> 3, lk = (t & 7) << 2;
  const int wk = t >> 4, wc = (t & 15) << 2;
  const long xBase = ((long)b * Nc + n0) * Cc;

#pragma unroll
  for (int rep = 0; rep < 4; ++rep) {
    const int v = t + rep * 256, r = v >> 4, c4 = (v & 15) << 2;
    *(float4*)&Ws2[r][c4] = *(const float4*)&Wsl[r * 64 + c4];
  }
  const float4 bsv = *(const float4*)&bsl[(tx << 2)];
  const float bs_[4] = {bsv.x, bsv.y, bsv.z, bsv.w};

  float4 acc4[4][4] = {};  // [i(tok)][q] over co quad

  for (int h = 0; h < Hc; ++h) {
    const int bh = b * Hc + h, colBase = h * 64;
    const float invt = 1.0f / fminf(fmaxf(temp[h], 0.1f), 5.0f);
    const float4 bxv = *(const float4*)&bx[colBase + (tx << 2)];
    const float bx_[4] = {bxv.x, bxv.y, bxv.z, bxv.w};

    // ---- stage 1: XM = X@Wx_h + bx ----
    float a1[4][4] = {};
    for (int kt = 0; kt < Cc; kt += 32) {
      const float4 x0 = *(const float4*)&X[xBase + (long)lr        * Cc + kt + lk];
      const float4 x1 = *(const float4*)&X[xBase + (long)(lr + 32) * Cc + kt + lk];
      const float4 g0 = *(const float4*)&Wx[(long)(kt + wk)      * INNERc + colBase + wc];
      const float4 g1 = *(const float4*)&Wx[(long)(kt + wk + 16) * INNERc + colBase + wc];
      __syncthreads();  // guards prev head's WTs/LgT reads vs As/Bs overwrite
      As[lk+0][lr] = x0.x; As[lk+1][lr] = x0.y; As[lk+2][lr] = x0.z; As[lk+3][lr] = x0.w;
      As[lk+0][lr+32] = x1.x; As[lk+1][lr+32] = x1.y; As[lk+2][lr+32] = x1.z; As[lk+3][lr+32] = x1.w;
      *(float4*)&Bs[wk][wc] = g0; *(float4*)&Bs[wk+16][wc] = g1;
      __syncthreads();
#pragma unroll
      for (int k = 0; k < 32; ++k) {
        const float4 a = *(const float4*)&As[k][ty << 2];
        fma4x4(a1, a, *(const float4*)&Bs[k][tx << 2]);
      }
    }
    __syncthreads();
#pragma unroll
    for (int i = 0; i < 4; ++i)
#pragma unroll
      for (int j = 0; j < 4; ++j)
        XMs[(tx<<2)+j][(ty<<2)+i] = a1[i][j] + bx_[j];   // [c][token]  (transposed!)
    __syncthreads();

    // ---- logits (contract over c=k) + softmax ----
    float l2[4][4] = {};
#pragma unroll
    for (int k = 0; k < 64; ++k) {
      const float4 a = *(const float4*)&XMs[k][ty << 2];
      fma4x4(l2, a, *(const float4*)&Ws2[k][tx << 2]);
    }
    float e[4][4];
#pragma unroll
    for (int i = 0; i < 4; ++i) {
      float mx = -1e30f;
#pragma unroll
      for (int j = 0; j < 4; ++j) { l2[i][j] = (l2[i][j] + bs_[j]) * invt; mx = fmaxf(mx, l2[i][j]); }
      for (int d = 1; d < 16; d <<= 1) mx = fmaxf(mx, __shfl_xor(mx, d));
      float s = 0.f;
#pragma unroll
      for (int j = 0; j < 4; ++j) { e[i][j] = __expf(l2[i][j] - mx); s += e[i][j]; }
      for (int d = 1; d < 16; d <<= 1) s += __shfl_xor(s, d);
      const float inv = 1.0f / s;
#pragma unroll
      for (int j = 0; j < 4; ++j) e[i][j] *= inv;
    }
    __syncthreads();  // XMs reads done before LgT overlay
#pragma unroll
    for (int i = 0; i < 4; ++i)
#pragma unroll
      for (int j = 0; j < 4; ++j)
        LgT[(tx<<2)+j][(ty<<2)+i] = e[i][j];   // [g][tok]
    __syncthreads();

    // ---- contract with WoT[bh] in g-chunks of 16 ----
    for (int gc = 0; gc < 4; ++gc) {
#pragma unroll
      for (int rep = 0; rep < 4; ++rep) {
        const int idx = t + rep * 256;           // 0..1023
        const int r = idx >> 6, q = (idx & 63) << 2;
        *(float4*)&WTs[r][q] = *(const float4*)&WoT[((long)bh * 64 + (gc<<4) + r) * 256 + q];
      }
      __syncthreads();
#pragma unroll
      for (int k = 0; k < 16; ++k) {
        const float4 a = *(const float4*)&LgT[(gc<<4) + k][ty << 2];
        const float av[4] = {a.x, a.y, a.z, a.w};
#pragma unroll
        for (int q = 0; q < 4; ++q) {
          const float4 w4 = *(const float4*)&WTs[k][(q<<6) + (tx<<2)];
#pragma unroll
          for (int i = 0; i < 4; ++i) {
            acc4[i][q].x += av[i]*w4.x; acc4[i][q].y += av[i]*w4.y;
            acc4[i][q].z += av[i]*w4.z; acc4[i][q].w += av[i]*w4.w;
          }
        }
      }
      __syncthreads();  // WTs reads done before next gc reload
    }
  }

#pragma unroll
  for (int q = 0; q < 4; ++q) {
    const float4 bov = *(const float4*)&bo[(q<<6) + (tx<<2)];
#pragma unroll
    for (int i = 0; i < 4; ++i) {
      float4 o;
      o.x = acc4[i][q].x + bov.x; o.y = acc4[i][q].y + bov.y;
      o.z = acc4[i][q].z + bov.z; o.w = acc4[i][q].w + bov.w;
      *(float4*)&out[((long)b * Nc + n0 + (ty<<2)+i) * 256 + (q<<6) + (tx<<2)] = o;
    }
  }
}

extern "C" void kernel_launch(void* const* d_in, const int* in_sizes, int n_in,
                              void* d_out, int out_size, void* d_ws, size_t ws_size,
                              hipStream_t stream)
{
  (void)in_sizes; (void)n_in; (void)out_size; (void)ws_size;
  const float* x    = (const float*)d_in[0];
  const float* xc   = (const float*)d_in[1];
  const float* Wfx  = (const float*)d_in[2];
  const float* bfx  = (const float*)d_in[3];
  const float* Wx   = (const float*)d_in[4];
  const float* bx   = (const float*)d_in[5];
  const float* Wsl  = (const float*)d_in[6];
  const float* bsl  = (const float*)d_in[7];
  const float* temp = (const float*)d_in[8];
  const float* Wq   = (const float*)d_in[9];
  const float* Wk   = (const float*)d_in[10];
  const float* Wv   = (const float*)d_in[11];
  const float* Wo   = (const float*)d_in[12];
  const float* bo   = (const float*)d_in[13];
  float* out = (float*)d_out;

  // workspace: 921,600 floats = 3.69 MB total
  float* ws  = (float*)d_ws;
  float* Sx  = ws;                 // 2048
  float* Sc  = Sx + 2048;          // 2048
  float* TUx = Sc + 2048;          // 131072
  float* TUc = TUx + 131072;       // 131072
  float* OT  = TUc + 131072;       // 131072
  float* WoT = OT + 131072;        // 524288

  hipMemsetAsync(Sx, 0, (size_t)(2 * 2048 + 2 * 131072) * sizeof(float), stream);

  project_token_kernel<<<dim3(16, 8, 4), 256, 0, stream>>>(xc, Wfx, bfx, Wx, bx, Wsl, bsl, temp, TUc, Sc);
  project_token_kernel<<<dim3(16, 8, 4), 256, 0, stream>>>(x,  Wfx, bfx, Wx, bx, Wsl, bsl, temp, TUx, Sx);
  att_kernel<<<dim3(32), dim3(64), 0, stream>>>(TUx, TUc, Sx, Sc, Wq, Wk, Wv, OT);
  wofold_kernel<<<dim3(4, 32), 256, 0, stream>>>(OT, Wo, WoT);
  outx_kernel<<<dim3(512, 4), 256, 0, stream>>>(x, Wx, bx, Wsl, bsl, temp, WoT, bo, out);
}